// Round 5
// baseline (1198.659 us; speedup 1.0000x reference)
//
#include <hip/hip_runtime.h>
#include <hip/hip_cooperative_groups.h>

#define D 128
#define CAP 3072        // coarse-bucket capacity (mean 2046, sigma ~45)

typedef __attribute__((ext_vector_type(8))) short short8;   // 8 bf16 (4 VGPRs)
typedef __attribute__((ext_vector_type(4))) float f32x4;    // MFMA acc

// bf16 helpers: packed storage = little-endian pairs in a uint (elem 2i = lo)
__device__ __forceinline__ float blo(unsigned w) { return __uint_as_float(w << 16); }
__device__ __forceinline__ float bhi(unsigned w) { return __uint_as_float(w & 0xFFFF0000u); }
__device__ __forceinline__ unsigned bpack(float a, float b) {   // RNE
    unsigned ua = __float_as_uint(a), ub = __float_as_uint(b);
    ua += 0x7FFFu + ((ua >> 16) & 1u);
    ub += 0x7FFFu + ((ub >> 16) & 1u);
    return (ua >> 16) | (ub & 0xFFFF0000u);
}

// ===========================================================================
// Stage bodies (shared by cooperative mega-kernel and the fallback path).
// SMEM: caller passes a 32 KB block; each body carves what it needs.
// Every body that reuses LDS across virtual-block iterations ends with
// __syncthreads() so the next iteration can't race the current one.
// ===========================================================================

__device__ __forceinline__ void dev_conv_x(int vb, int tid, const float* x,
                                           unsigned* A1, int N) {
    int idx = vb * 256 + tid;
    if (idx < N * 32) {
        int n = idx >> 5, q = idx & 31;
        float4 v = ((const float4*)x)[idx];
        uint2 o;
        o.x = bpack(v.x, v.y);
        o.y = bpack(v.z, v.w);
        *(uint2*)(A1 + (size_t)n * 128 + 64 + q * 2) = o;
    }
}

__device__ __forceinline__ void dev_prep_w(int vb, int tid,
        const float* WI1, const float* WO1, const float* WI2, const float* WO2,
        unsigned* Wt1, unsigned* Wt2) {
    int layer = vb >> 6;
    const float* WI = layer ? WI2 : WI1;
    const float* WO = layer ? WO2 : WO1;
    unsigned* Wt = layer ? Wt2 : Wt1;
    int idx = (vb & 63) * 256 + tid;          // 0..16383
    int j = idx >> 7;
    int kk = idx & 127;
    int k0 = kk * 2;
    float a, b;
    if (k0 < D) {
        a = WI[j * D + k0];
        b = WI[j * D + k0 + 1];
    } else {
        int kx = k0 - D;
        a = WI[j * D + kx]     + WO[j * D + kx];
        b = WI[j * D + kx + 1] + WO[j * D + kx + 1];
    }
    Wt[idx] = bpack(a, b);
}

__device__ __forceinline__ void dev_prep_c(int tid,
        const float* WI1, const float* WI2, const float* b1, const float* b2,
        const float* rel1, const float* rel2, float* c1, float* c2) {
    int layer = tid >> 7;
    int j = tid & (D - 1);
    const float* WI = layer ? WI2 : WI1;
    const float* b  = layer ? b2  : b1;
    const float* rl = layer ? rel2 : rel1;
    float s = b[j];
    for (int k = 0; k < D; ++k) s = fmaf(-WI[j * D + k], rl[k], s);
    (layer ? c2 : c1)[j] = s;
}

__device__ __forceinline__ void dev_conv_rel(int vb, int tid,
        const float* rel1, const float* rel2,
        unsigned* rb1, unsigned* rb2, int relHalf) {
    int idx = vb * 256 + tid;
    if (idx < 2 * relHalf) {
        const float* src = (idx < relHalf) ? rel1 : rel2;
        unsigned* dst = (idx < relHalf) ? rb1 : rb2;
        int k = (idx < relHalf) ? idx : idx - relHalf;
        float4 v = ((const float4*)src)[k];
        uint2 o;
        o.x = bpack(v.x, v.y);
        o.y = bpack(v.z, v.w);
        *(uint2*)(dst + (size_t)k * 2) = o;
    }
}

// bucket1: coarse bucket sort, 4096 edges per virtual block, 64B-padded
// claim counters (proven r3). SMEM: pay 16K | ck 8K | hist 1.6K | base 1.6K.
__device__ __forceinline__ void dev_bucket1(char* SMEM, int vb,
        const int* srcA, const int* dstA, const int* etA,
        int* coarseCnt, unsigned* bulk, int E, int nCoarse) {
    unsigned* pay = (unsigned*)SMEM;
    unsigned short* ck = (unsigned short*)(SMEM + 16384);
    int* hist = (int*)(SMEM + 24576);
    int* base = (int*)(SMEM + 26176);
    int tid = threadIdx.x;
    int e0 = vb * 4096;
    int cnt = E - e0; if (cnt > 4096) cnt = 4096;
    for (int i = tid; i < nCoarse; i += 256) hist[i] = 0;
    __syncthreads();
    for (int i = tid; i < cnt; i += 256) {
        int e = e0 + i;
        int d = dstA[e];
        pay[i] = (unsigned)srcA[e] | ((unsigned)etA[e] << 17) | ((unsigned)(d & 127) << 25);
        int c = d >> 7;
        ck[i] = (unsigned short)c;
        atomicAdd(&hist[c], 1);
    }
    __syncthreads();
    for (int i = tid; i < nCoarse; i += 256) {
        int h = hist[i];
        base[i] = (h > 0) ? (i * CAP + atomicAdd(&coarseCnt[i * 16], h)) : 0;
        hist[i] = 0;
    }
    __syncthreads();
    for (int i = tid; i < cnt; i += 256) {
        int c = ck[i];
        int pos = base[c] + atomicAdd(&hist[c], 1);
        bulk[pos] = pay[i];
    }
    __syncthreads();              // LDS reuse guard for next virtual block
}

// bucket2 (scan fused): per coarse bucket, reduce padded counters below it
// (device-scope atomic loads -> cross-XCD fresh), fine histogram + scan,
// write row_ptr, scatter to col. SMEM: pay 12K | red 1K | hist .5K | cur .5K.
__device__ __forceinline__ void dev_bucket2(char* SMEM, int c,
        const unsigned* bulk, int* coarseCnt,
        int* row_ptr, int* col, int N, int E, int nCoarse) {
    unsigned* pay = (unsigned*)SMEM;
    int* red  = (int*)(SMEM + 12288);
    int* hist = (int*)(SMEM + 13312);
    int* cur  = (int*)(SMEM + 13824);
    int tid = threadIdx.x;
    int cnt = __hip_atomic_load(&coarseCnt[c * 16], __ATOMIC_RELAXED,
                                __HIP_MEMORY_SCOPE_AGENT);
    const unsigned* seg = bulk + (size_t)c * CAP;
    if (tid < 128) hist[tid] = 0;
    int sum = 0;
    for (int i = tid; i < c; i += 256)
        sum += __hip_atomic_load(&coarseCnt[i * 16], __ATOMIC_RELAXED,
                                 __HIP_MEMORY_SCOPE_AGENT);
    red[tid] = sum;
    __syncthreads();
    for (int off = 128; off > 0; off >>= 1) {
        if (tid < off) red[tid] += red[tid + off];
        __syncthreads();
    }
    int cb = red[0];                        // exclusive coarse base
    for (int i = tid; i < cnt; i += 256) {
        unsigned v = seg[i];
        pay[i] = v;
        atomicAdd(&hist[v >> 25], 1);
    }
    __syncthreads();
    int f = tid;
    int myCnt = (f < 128) ? hist[f] : 0;
    for (int off = 1; off < 128; off <<= 1) {
        int v = (f < 128 && f >= off) ? hist[f - off] : 0;
        __syncthreads();
        if (f < 128) hist[f] += v;
        __syncthreads();
    }
    if (f < 128) {
        int excl = hist[f] - myCnt;
        int d = (c << 7) + f;
        if (d < N) row_ptr[d] = cb + excl;
        cur[f] = cb + excl;
    }
    if (c == nCoarse - 1 && tid == 0) row_ptr[N] = E;
    __syncthreads();
    for (int i = tid; i < cnt; i += 256) {
        unsigned v = pay[i];
        int pos = atomicAdd(&cur[v >> 25], 1);
        col[pos] = (int)(v & 0x1FFFFFFu);
    }
    __syncthreads();              // LDS reuse guard
}

// gather v2 (r1/r3-proven): one wave per node; col prefetch + shfl
// distribute; 8x16B loads in flight. Asrc x-part at uint offset 64 of the
// 128-uint row; Adst agg at offset 0. No block barriers, no returns.
__device__ __forceinline__ void dev_gather(int n, int lane,
        const unsigned* Asrc, const int* col, const int* row_ptr,
        const unsigned* relb, unsigned* Adst) {
    int g = lane >> 4;                       // edge slot 0..3
    int h = lane & 15;                       // dim chunk 0..15
    int beg = row_ptr[n];
    int end = row_ptr[n + 1];
    float s[8];
#pragma unroll
    for (int j = 0; j < 8; ++j) s[j] = 0.f;

    for (int base = beg; base < end; base += 64) {
        int ci = base + lane;
        unsigned cv = (unsigned)col[(ci < end) ? ci : beg];   // in-bounds
        int mm = end - base; if (mm > 64) mm = 64;
        int e = 0;
        for (; e + 16 <= mm; e += 16) {
            uint4 u[4], r[4];
#pragma unroll
            for (int t = 0; t < 4; ++t) {
                unsigned c = (unsigned)__shfl((int)cv, e + 4 * t + g, 64);
                u[t] = ((const uint4*)(Asrc + (size_t)(c & 0x1FFFFu) * 128 + 64))[h];
                r[t] = ((const uint4*)(relb + (size_t)(c >> 17) * 64))[h];
            }
#pragma unroll
            for (int t = 0; t < 4; ++t) {
                s[0] += blo(u[t].x) - blo(r[t].x);
                s[1] += bhi(u[t].x) - bhi(r[t].x);
                s[2] += blo(u[t].y) - blo(r[t].y);
                s[3] += bhi(u[t].y) - bhi(r[t].y);
                s[4] += blo(u[t].z) - blo(r[t].z);
                s[5] += bhi(u[t].z) - bhi(r[t].z);
                s[6] += blo(u[t].w) - blo(r[t].w);
                s[7] += bhi(u[t].w) - bhi(r[t].w);
            }
        }
        for (; e + 4 <= mm; e += 4) {
            unsigned c = (unsigned)__shfl((int)cv, e + g, 64);
            uint4 u = ((const uint4*)(Asrc + (size_t)(c & 0x1FFFFu) * 128 + 64))[h];
            uint4 r = ((const uint4*)(relb + (size_t)(c >> 17) * 64))[h];
            s[0] += blo(u.x) - blo(r.x);
            s[1] += bhi(u.x) - bhi(r.x);
            s[2] += blo(u.y) - blo(r.y);
            s[3] += bhi(u.y) - bhi(r.y);
            s[4] += blo(u.z) - blo(r.z);
            s[5] += bhi(u.z) - bhi(r.z);
            s[6] += blo(u.w) - blo(r.w);
            s[7] += bhi(u.w) - bhi(r.w);
        }
        if (e < mm) {
            int idx = e + g;
            unsigned c = (unsigned)__shfl((int)cv, (idx < mm) ? idx : 0, 64);
            if (idx < mm) {
                uint4 u = ((const uint4*)(Asrc + (size_t)(c & 0x1FFFFu) * 128 + 64))[h];
                uint4 r = ((const uint4*)(relb + (size_t)(c >> 17) * 64))[h];
                s[0] += blo(u.x) - blo(r.x);
                s[1] += bhi(u.x) - bhi(r.x);
                s[2] += blo(u.y) - blo(r.y);
                s[3] += bhi(u.y) - bhi(r.y);
                s[4] += blo(u.z) - blo(r.z);
                s[5] += bhi(u.z) - bhi(r.z);
                s[6] += blo(u.w) - blo(r.w);
                s[7] += bhi(u.w) - bhi(r.w);
            }
        }
    }
#pragma unroll
    for (int j = 0; j < 8; ++j) {
        s[j] += __shfl_xor(s[j], 16, 64);
        s[j] += __shfl_xor(s[j], 32, 64);
    }
    if (g == 0) {
        uint4 o;
        o.x = bpack(s[0], s[1]);
        o.y = bpack(s[2], s[3]);
        o.z = bpack(s[4], s[5]);
        o.w = bpack(s[6], s[7]);
        ((uint4*)(Adst + (size_t)n * 128))[h] = o;
    }
}

// node GEMM (r3-proven): 128 nodes per virtual block, 4 waves, K=256 in 4
// chunks of 64, XOR-swizzled LDS, conflict-free b128. Trailing sync per kc
// makes it safe under virtual-block iteration; epilogue is register-only.
__device__ __forceinline__ void dev_mfma(char* SMEM, int vb,
        const unsigned* A, const unsigned* Wt, const float* cvec,
        float* outf, unsigned* outb, int do_relu, int N) {
    unsigned* WtS = (unsigned*)SMEM;            // 16 KB
    unsigned* AS  = (unsigned*)(SMEM + 16384);  // 16 KB
    int tid = threadIdx.x;
    int w = tid >> 6;
    int lane = tid & 63;
    int m = lane & 15;
    int quad = lane >> 4;
    int nbase = vb * 128;

    f32x4 acc[2][8];
#pragma unroll
    for (int nt = 0; nt < 2; ++nt)
#pragma unroll
        for (int t = 0; t < 8; ++t) acc[nt][t] = (f32x4)(0.f);

    for (int kc = 0; kc < 4; ++kc) {
        for (int i = tid; i < 1024; i += 256) {
            int j = i >> 3, q = i & 7;
            uint4 v = ((const uint4*)Wt)[j * 32 + kc * 8 + q];
            *(uint4*)&WtS[j * 32 + 4 * (q ^ (j & 7))] = v;
        }
        for (int i = tid; i < 1024; i += 256) {
            int n = i >> 3, q = i & 7;
            int gn = nbase + n;
            uint4 v = make_uint4(0u, 0u, 0u, 0u);
            if (gn < N) v = ((const uint4*)A)[(size_t)gn * 32 + kc * 8 + q];
            *(uint4*)&AS[n * 32 + 4 * (q ^ (n & 7))] = v;
        }
        __syncthreads();

#pragma unroll
        for (int s = 0; s < 2; ++s) {
            int g = s * 4 + quad;
            int r0 = w * 32 + m;
            int r1 = r0 + 16;
            short8 b0 = *(const short8*)&AS[r0 * 32 + 4 * (g ^ (r0 & 7))];
            short8 b1 = *(const short8*)&AS[r1 * 32 + 4 * (g ^ (r1 & 7))];
#pragma unroll
            for (int t = 0; t < 8; ++t) {
                int jr = t * 16 + m;
                short8 a = *(const short8*)&WtS[jr * 32 + 4 * (g ^ (jr & 7))];
                acc[0][t] = __builtin_amdgcn_mfma_f32_16x16x32_bf16(a, b0, acc[0][t], 0, 0, 0);
                acc[1][t] = __builtin_amdgcn_mfma_f32_16x16x32_bf16(a, b1, acc[1][t], 0, 0, 0);
            }
        }
        __syncthreads();
    }

#pragma unroll
    for (int nt = 0; nt < 2; ++nt) {
        int node = nbase + w * 32 + nt * 16 + m;
        if (node < N) {
#pragma unroll
            for (int t = 0; t < 8; ++t) {
                float4 cv = ((const float4*)cvec)[t * 4 + quad];
                f32x4 a = acc[nt][t];
                float v0 = a[0] + cv.x;
                float v1 = a[1] + cv.y;
                float v2 = a[2] + cv.z;
                float v3 = a[3] + cv.w;
                if (do_relu) {
                    v0 = fmaxf(v0, 0.f); v1 = fmaxf(v1, 0.f);
                    v2 = fmaxf(v2, 0.f); v3 = fmaxf(v3, 0.f);
                }
                if (outf) {
                    ((float4*)outf)[(size_t)node * 32 + t * 4 + quad] =
                        make_float4(v0, v1, v2, v3);
                } else {
                    uint2 o;
                    o.x = bpack(v0, v1);
                    o.y = bpack(v2, v3);
                    ((uint2*)(outb + (size_t)node * 128))[32 + t * 4 + quad] = o;
                }
            }
        }
    }
}

// ===========================================================================
// Cooperative mega-kernel: whole pipeline, 6 grid syncs, 1 dispatch.
// ===========================================================================
__global__ __launch_bounds__(256, 4) void mega_kernel(
    const float* __restrict__ x,
    const int* __restrict__ srcA, const int* __restrict__ dstA,
    const int* __restrict__ etA,
    const float* __restrict__ WI1, const float* __restrict__ WO1,
    const float* __restrict__ WI2, const float* __restrict__ WO2,
    const float* __restrict__ rel1, const float* __restrict__ rel2,
    const float* __restrict__ b1, const float* __restrict__ b2,
    unsigned* A1, unsigned* A2,
    unsigned* __restrict__ Wt1, unsigned* __restrict__ Wt2,
    float* __restrict__ c1, float* __restrict__ c2,
    unsigned* __restrict__ rb1, unsigned* __restrict__ rb2,
    int* coarseCnt, unsigned* __restrict__ bulk,
    int* __restrict__ row_ptr, int* __restrict__ col,
    int N, int E, int relHalf, int nCoarse) {
    __shared__ __align__(16) char SM[32768];
    cooperative_groups::grid_group grid = cooperative_groups::this_grid();
    int tid = threadIdx.x;
    const int G = gridDim.x;

    // ---- stage 0: conv_x + prep_w + prep_c + conv_rel + zero counters ----
    const int CB = (N * 32 + 255) / 256;
    const int RB = (2 * relHalf + 255) / 256;
    const int T0 = CB + 128 + 1 + RB + 1;
    for (int vb = blockIdx.x; vb < T0; vb += G) {
        if (vb < CB) dev_conv_x(vb, tid, x, A1, N);
        else if (vb < CB + 128) dev_prep_w(vb - CB, tid, WI1, WO1, WI2, WO2, Wt1, Wt2);
        else if (vb == CB + 128) dev_prep_c(tid, WI1, WI2, b1, b2, rel1, rel2, c1, c2);
        else if (vb < CB + 129 + RB) dev_conv_rel(vb - (CB + 129), tid, rel1, rel2, rb1, rb2, relHalf);
        else { for (int i = tid; i < 8192; i += 256) coarseCnt[i] = 0; }
    }
    __threadfence(); grid.sync(); __threadfence();

    // ---- stage 1: bucket1 ----
    const int B1B = (E + 4095) / 4096;
    for (int vb = blockIdx.x; vb < B1B; vb += G)
        dev_bucket1(SM, vb, srcA, dstA, etA, coarseCnt, bulk, E, nCoarse);
    __threadfence(); grid.sync(); __threadfence();

    // ---- stage 2: bucket2 (CSR finish) ----
    for (int vb = blockIdx.x; vb < nCoarse; vb += G)
        dev_bucket2(SM, vb, bulk, coarseCnt, row_ptr, col, N, E, nCoarse);
    __threadfence(); grid.sync(); __threadfence();

    // ---- stage 3: gather layer 1 ----
    const int GQ = (N + 3) / 4;
    for (int vb = blockIdx.x; vb < GQ; vb += G) {
        int n = vb * 4 + (tid >> 6);
        if (n < N) dev_gather(n, tid & 63, A1, col, row_ptr, rb1, A1);
    }
    __threadfence(); grid.sync(); __threadfence();

    // ---- stage 4: node GEMM layer 1 -> bf16 x-part of A2 ----
    const int MB = (N + 127) / 128;
    for (int vb = blockIdx.x; vb < MB; vb += G)
        dev_mfma(SM, vb, A1, Wt1, c1, (float*)nullptr, A2, 1, N);
    __threadfence(); grid.sync(); __threadfence();

    // ---- stage 5: gather layer 2 ----
    for (int vb = blockIdx.x; vb < GQ; vb += G) {
        int n = vb * 4 + (tid >> 6);
        if (n < N) dev_gather(n, tid & 63, A2, col, row_ptr, rb2, A2);
    }
    __threadfence(); grid.sync(); __threadfence();

    // ---- stage 6: node GEMM layer 2 -> fp32 out (in place over A2) ----
    for (int vb = blockIdx.x; vb < MB; vb += G)
        dev_mfma(SM, vb, A2, Wt2, c2, (float*)A2, (unsigned*)nullptr, 0, N);
}

// ===========================================================================
// Fallback kernels (exact r3 sequence) in case cooperative launch fails.
// ===========================================================================
__global__ __launch_bounds__(256) void k_setup(
    const float* __restrict__ x,
    const int* __restrict__ srcA, const int* __restrict__ dstA,
    const int* __restrict__ etA,
    const float* __restrict__ WI1, const float* __restrict__ WO1,
    const float* __restrict__ WI2, const float* __restrict__ WO2,
    const float* __restrict__ rel1, const float* __restrict__ rel2,
    const float* __restrict__ b1, const float* __restrict__ b2,
    unsigned* __restrict__ A1,
    unsigned* __restrict__ Wt1, unsigned* __restrict__ Wt2,
    float* __restrict__ c1, float* __restrict__ c2,
    unsigned* __restrict__ rb1, unsigned* __restrict__ rb2,
    int* coarseCnt, unsigned* __restrict__ bulk,
    int N, int E, int relHalf, int nCoarse) {
    __shared__ __align__(16) char SM[32768];
    int bx = blockIdx.x;
    const int B1B = (E + 4095) / 4096;
    const int CB = (N * 32 + 255) / 256;
    if (bx < B1B) { dev_bucket1(SM, bx, srcA, dstA, etA, coarseCnt, bulk, E, nCoarse); return; }
    bx -= B1B;
    if (bx < CB) { dev_conv_x(bx, threadIdx.x, x, A1, N); return; }
    bx -= CB;
    if (bx < 128) { dev_prep_w(bx, threadIdx.x, WI1, WO1, WI2, WO2, Wt1, Wt2); return; }
    bx -= 128;
    if (bx == 0) { dev_prep_c(threadIdx.x, WI1, WI2, b1, b2, rel1, rel2, c1, c2); return; }
    bx -= 1;
    dev_conv_rel(bx, threadIdx.x, rel1, rel2, rb1, rb2, relHalf);
}

__global__ __launch_bounds__(256) void k_bucket2(const unsigned* __restrict__ bulk,
        int* coarseCnt, int* __restrict__ row_ptr, int* __restrict__ col,
        int N, int E, int nCoarse) {
    __shared__ __align__(16) char SM[32768];
    dev_bucket2(SM, blockIdx.x, bulk, coarseCnt, row_ptr, col, N, E, nCoarse);
}

__global__ __launch_bounds__(256) void k_gather(const unsigned* __restrict__ Asrc,
        const int* __restrict__ col, const int* __restrict__ row_ptr,
        const unsigned* __restrict__ relb, unsigned* __restrict__ Adst, int N) {
    int n = blockIdx.x * 4 + (threadIdx.x >> 6);
    if (n < N) dev_gather(n, threadIdx.x & 63, Asrc, col, row_ptr, relb, Adst);
}

__global__ __launch_bounds__(256) void k_mfma(const unsigned* A,
        const unsigned* __restrict__ Wt, const float* __restrict__ cvec,
        float* outf, unsigned* outb, int do_relu, int N) {
    __shared__ __align__(16) char SM[32768];
    dev_mfma(SM, blockIdx.x, A, Wt, cvec, outf, outb, do_relu, N);
}

extern "C" void kernel_launch(void* const* d_in, const int* in_sizes, int n_in,
                              void* d_out, int out_size, void* d_ws, size_t ws_size,
                              hipStream_t stream) {
    const float* x    = (const float*)d_in[0];
    const int*   ei   = (const int*)d_in[1];
    const int*   et   = (const int*)d_in[2];
    const float* WI1  = (const float*)d_in[3];
    const float* WO1  = (const float*)d_in[4];
    const float* rel1 = (const float*)d_in[5];
    const float* b1   = (const float*)d_in[6];
    const float* WI2  = (const float*)d_in[7];
    const float* WO2  = (const float*)d_in[8];
    const float* rel2 = (const float*)d_in[9];
    const float* b2   = (const float*)d_in[10];

    const int E = in_sizes[2];          // 800000
    const int N = in_sizes[0] / D;      // 50000
    const int* src = ei;
    const int* dst = ei + E;
    const int nCoarse = (N + 127) / 128;   // 391

    // workspace layout (uints), A2 lives in d_out
    unsigned* wsu  = (unsigned*)d_ws;
    unsigned* A1   = wsu;                          // N*128 uints (25.6 MB)
    unsigned* Wt1  = A1 + (size_t)N * 128;         // 16384
    unsigned* Wt2  = Wt1 + 16384;                  // 16384
    float*    cvec1 = (float*)(Wt2 + 16384);       // 128
    float*    cvec2 = cvec1 + D;                   // 128
    unsigned* rb1  = (unsigned*)(cvec2 + D);       // 237*64
    unsigned* rb2  = rb1 + 237 * 64;               // 237*64
    int*      coarseCnt  = (int*)(rb2 + 237 * 64); // nCoarse*16 padded (64B/counter)
    int*      row_ptr    = coarseCnt + 8192;       // N+4
    int*      col        = row_ptr + N + 4;        // E
    unsigned* bulk       = (unsigned*)(col + E);   // nCoarse*CAP (4.8 MB)

    unsigned* A2 = (unsigned*)d_out;               // [N][128] uints -> fp32 out

    const int relHalf = 237 * 32;                  // float4s per rel table
    const int B1B = (E + 4095) / 4096;             // 196
    const int CB = (N * 32 + 255) / 256;           // 6250
    const int RB = (2 * relHalf + 255) / 256;      // 60

    // ---- cooperative path: compute a co-residency-safe grid once ----
    static int s_grid = -2;        // -2 = not probed, -1 = coop unusable
    if (s_grid == -2) {
        int dev = 0;
        (void)hipGetDevice(&dev);
        int cus = 0;
        if (hipDeviceGetAttribute(&cus, hipDeviceAttributeMultiprocessorCount,
                                  dev) != hipSuccess || cus <= 0) cus = 256;
        int bpc = 0;
        hipError_t oe = hipOccupancyMaxActiveBlocksPerMultiprocessor(
            &bpc, reinterpret_cast<const void*>(&mega_kernel), 256, 0);
        if (oe == hipSuccess && bpc > 0) {
            long g = (long)bpc * cus;
            if (g > 2048) g = 2048;
            s_grid = (int)g;
        } else {
            s_grid = -1;
        }
    }

    static bool s_coop_ok = true;
    if (s_grid > 0 && s_coop_ok) {
        int Nv = N, Ev = E, rhv = relHalf, ncv = nCoarse;
        void* kargs[] = {
            (void*)&x, (void*)&src, (void*)&dst, (void*)&et,
            (void*)&WI1, (void*)&WO1, (void*)&WI2, (void*)&WO2,
            (void*)&rel1, (void*)&rel2, (void*)&b1, (void*)&b2,
            (void*)&A1, (void*)&A2,
            (void*)&Wt1, (void*)&Wt2, (void*)&cvec1, (void*)&cvec2,
            (void*)&rb1, (void*)&rb2,
            (void*)&coarseCnt, (void*)&bulk, (void*)&row_ptr, (void*)&col,
            (void*)&Nv, (void*)&Ev, (void*)&rhv, (void*)&ncv };
        hipError_t err = hipLaunchCooperativeKernel(
            reinterpret_cast<const void*>(&mega_kernel),
            dim3((unsigned)s_grid), dim3(256), kargs, 0, stream);
        if (err == hipSuccess) return;
        s_coop_ok = false;         // fall through to classic path
    }

    // ---- fallback: exact r3 dispatch sequence ----
    hipMemsetAsync(coarseCnt, 0, 8192 * sizeof(int), stream);
    k_setup<<<B1B + CB + 128 + 1 + RB, 256, 0, stream>>>(
        x, src, dst, et, WI1, WO1, WI2, WO2, rel1, rel2, b1, b2,
        A1, Wt1, Wt2, cvec1, cvec2, rb1, rb2,
        coarseCnt, bulk, N, E, relHalf, nCoarse);
    k_bucket2<<<nCoarse, 256, 0, stream>>>(bulk, coarseCnt, row_ptr, col,
                                           N, E, nCoarse);
    const int gather_blocks = (N + 3) / 4;
    const int node_blocks = (N + 127) / 128;
    k_gather<<<gather_blocks, 256, 0, stream>>>(A1, col, row_ptr, rb1, A1, N);
    k_mfma<<<node_blocks, 256, 0, stream>>>(A1, Wt1, cvec1,
                                            (float*)nullptr, A2, 1, N);
    k_gather<<<gather_blocks, 256, 0, stream>>>(A2, col, row_ptr, rb2, A2, N);
    k_mfma<<<node_blocks, 256, 0, stream>>>(A2, Wt2, cvec2,
                                            (float*)d_out, (unsigned*)nullptr, 0, N);
}

// Round 6
// 274.573 us; speedup vs baseline: 4.3655x; 4.3655x over previous
//
#include <hip/hip_runtime.h>

#define D 128
#define CAP 3072        // coarse-bucket capacity (mean 2046, sigma ~45)

typedef __attribute__((ext_vector_type(8))) short short8;   // 8 bf16 (4 VGPRs)
typedef __attribute__((ext_vector_type(4))) float f32x4;    // MFMA acc

// bf16 helpers: packed storage = little-endian pairs in a uint (elem 2i = lo)
__device__ __forceinline__ float blo(unsigned w) { return __uint_as_float(w << 16); }
__device__ __forceinline__ float bhi(unsigned w) { return __uint_as_float(w & 0xFFFF0000u); }
__device__ __forceinline__ unsigned bpack(float a, float b) {   // RNE
    unsigned ua = __float_as_uint(a), ub = __float_as_uint(b);
    ua += 0x7FFFu + ((ua >> 16) & 1u);
    ub += 0x7FFFu + ((ub >> 16) & 1u);
    return (ua >> 16) | (ub & 0xFFFF0000u);
}

// ---------------------------------------------------------------------------
// setup_mega (r3-proven): ONE dispatch for all independent prep + bucket1:
//   blocks [0, B1B)        : bucket1 (coarse sort, 4096 edges/block,
//                            64B-padded claim counters)
//   blocks [B1B, +CB)      : conv_x  (fp32 x -> bf16 X1 rows [N][64])
//   blocks [.., +128)      : prep_w  (Wt bf16, 64 blocks per layer)
//   block  next            : prep_c  (cvec, both layers)
//   blocks [.., +RB)       : conv_rel (rel fp32 -> bf16)
// coarseCnt must be zeroed (hipMemsetAsync) before this kernel.
// ---------------------------------------------------------------------------
__global__ __launch_bounds__(256) void setup_mega(
    const float* __restrict__ x,
    const int* __restrict__ srcA, const int* __restrict__ dstA,
    const int* __restrict__ etA,
    const float* __restrict__ WI1, const float* __restrict__ WO1,
    const float* __restrict__ WI2, const float* __restrict__ WO2,
    const float* __restrict__ rel1, const float* __restrict__ rel2,
    const float* __restrict__ b1, const float* __restrict__ b2,
    unsigned* __restrict__ X1,
    unsigned* __restrict__ Wt1, unsigned* __restrict__ Wt2,
    float* __restrict__ c1, float* __restrict__ c2,
    unsigned* __restrict__ rb1, unsigned* __restrict__ rb2,
    int* __restrict__ coarseCnt, unsigned* __restrict__ bulk,
    int N, int E, int relHalf, int nCoarse) {
    int tid = threadIdx.x;
    int bx = blockIdx.x;
    const int B1B = (E + 4095) / 4096;

    if (bx < B1B) {                               // ---- bucket1 ----
        __shared__ unsigned pay[4096];
        __shared__ unsigned short ck[4096];
        __shared__ int hist[400];
        __shared__ int base[400];
        int e0 = bx * 4096;
        int cnt = E - e0; if (cnt > 4096) cnt = 4096;
        for (int i = tid; i < nCoarse; i += 256) hist[i] = 0;
        __syncthreads();
        for (int i = tid; i < cnt; i += 256) {
            int e = e0 + i;
            int d = dstA[e];
            pay[i] = (unsigned)srcA[e] | ((unsigned)etA[e] << 17) | ((unsigned)(d & 127) << 25);
            int c = d >> 7;
            ck[i] = (unsigned short)c;
            atomicAdd(&hist[c], 1);
        }
        __syncthreads();
        for (int i = tid; i < nCoarse; i += 256) {
            int h = hist[i];
            base[i] = (h > 0) ? (i * CAP + atomicAdd(&coarseCnt[i * 16], h)) : 0;
            hist[i] = 0;
        }
        __syncthreads();
        for (int i = tid; i < cnt; i += 256) {
            int c = ck[i];
            int pos = base[c] + atomicAdd(&hist[c], 1);
            bulk[pos] = pay[i];
        }
        return;
    }
    bx -= B1B;
    const int CB = (N * 32 + 255) / 256;
    if (bx < CB) {                                // ---- conv_x ----
        int idx = bx * 256 + tid;
        if (idx < N * 32) {
            int n = idx >> 5, q = idx & 31;
            float4 v = ((const float4*)x)[idx];
            uint2 o;
            o.x = bpack(v.x, v.y);
            o.y = bpack(v.z, v.w);
            *(uint2*)(X1 + (size_t)n * 64 + q * 2) = o;
        }
        return;
    }
    bx -= CB;
    if (bx < 128) {                               // ---- prep_w ----
        int layer = bx >> 6;
        const float* WI = layer ? WI2 : WI1;
        const float* WO = layer ? WO2 : WO1;
        unsigned* Wt = layer ? Wt2 : Wt1;
        int idx = (bx & 63) * 256 + tid;          // 0..16383
        int j = idx >> 7;
        int kk = idx & 127;
        int k0 = kk * 2;
        float a, b;
        if (k0 < D) {
            a = WI[j * D + k0];
            b = WI[j * D + k0 + 1];
        } else {
            int kx = k0 - D;
            a = WI[j * D + kx]     + WO[j * D + kx];
            b = WI[j * D + kx + 1] + WO[j * D + kx + 1];
        }
        Wt[idx] = bpack(a, b);
        return;
    }
    bx -= 128;
    if (bx == 0) {                                // ---- prep_c ----
        int layer = tid >> 7;
        int j = tid & (D - 1);
        const float* WI = layer ? WI2 : WI1;
        const float* b  = layer ? b2  : b1;
        const float* rl = layer ? rel2 : rel1;
        float s = b[j];
        for (int k = 0; k < D; ++k) s = fmaf(-WI[j * D + k], rl[k], s);
        (layer ? c2 : c1)[j] = s;
        return;
    }
    bx -= 1;
    {                                             // ---- conv_rel ----
        int idx = bx * 256 + tid;
        if (idx < 2 * relHalf) {
            const float* src = (idx < relHalf) ? rel1 : rel2;
            unsigned* dst = (idx < relHalf) ? rb1 : rb2;
            int k = (idx < relHalf) ? idx : idx - relHalf;
            float4 v = ((const float4*)src)[k];
            uint2 o;
            o.x = bpack(v.x, v.y);
            o.y = bpack(v.z, v.w);
            *(uint2*)(dst + (size_t)k * 2) = o;
        }
    }
}

// ---------------------------------------------------------------------------
// bucket2 (scan fused, r3-proven): one block per coarse bucket. Reduces the
// padded coarse counters below it for its global base, fine-histograms 128
// bins, scans, writes row_ptr, scatters to col.
// ---------------------------------------------------------------------------
__global__ __launch_bounds__(256) void bucket2(const unsigned* __restrict__ bulk,
                                               const int* __restrict__ coarseCnt,
                                               int* __restrict__ row_ptr,
                                               int* __restrict__ col,
                                               int N, int E, int nCoarse) {
    __shared__ unsigned pay[CAP];
    __shared__ int red[256];
    __shared__ int hist[128];
    __shared__ int cur[128];
    int c = blockIdx.x;
    int tid = threadIdx.x;
    int cnt = coarseCnt[c * 16];
    const unsigned* seg = bulk + (size_t)c * CAP;
    if (tid < 128) hist[tid] = 0;
    int sum = 0;
    for (int i = tid; i < c; i += 256) sum += coarseCnt[i * 16];
    red[tid] = sum;
    __syncthreads();
    for (int off = 128; off > 0; off >>= 1) {
        if (tid < off) red[tid] += red[tid + off];
        __syncthreads();
    }
    int cb = red[0];                        // exclusive coarse base
    for (int i = tid; i < cnt; i += 256) {
        unsigned v = seg[i];
        pay[i] = v;
        atomicAdd(&hist[v >> 25], 1);
    }
    __syncthreads();
    // exclusive scan of 128 fine bins (threads 0..127)
    int f = tid;
    int myCnt = (f < 128) ? hist[f] : 0;
    for (int off = 1; off < 128; off <<= 1) {
        int v = (f < 128 && f >= off) ? hist[f - off] : 0;
        __syncthreads();
        if (f < 128) hist[f] += v;
        __syncthreads();
    }
    if (f < 128) {
        int excl = hist[f] - myCnt;
        int d = (c << 7) + f;
        if (d < N) row_ptr[d] = cb + excl;
        cur[f] = cb + excl;
    }
    if (c == nCoarse - 1 && tid == 0) row_ptr[N] = E;
    __syncthreads();
    for (int i = tid; i < cnt; i += 256) {
        unsigned v = pay[i];
        int pos = atomicAdd(&cur[v >> 25], 1);
        col[pos] = (int)(v & 0x1FFFFFFu);
    }
}

// ---------------------------------------------------------------------------
// fused_layer v2: gather + MFMA GEMM, ONE kernel, 16 KB LDS (occupancy fix
// over r4's 32 KB). 64 nodes/block, 256 thr = 4 waves x 16 nodes.
// Phase 1 (gather): identical to r4 (col prefetch + shfl distribute, 8x16B
//   in flight), writes bf16 agg into aggS in the XOR-swizzled MFMA layout.
// Phase 2 (GEMM): NO WtS staging -- A-operand fragments read directly from
//   global Wt (128 KB, L2-hot; ~200 MB aggregate L2 traffic ~ 6 us). kc<2
//   B-operand from aggS, kc>=2 from global X rows. Zero staging barriers:
//   each wave reads only aggS rows it wrote itself (one safety barrier).
// LDS 16 KB -> 8 blocks/CU (wave-slot cap) vs r4's 3 -> gather-phase TLP
// ~2.7x. No aliasing: reads X, writes X2 (layer1) or fp32 d_out (layer2).
// ---------------------------------------------------------------------------
__global__ __launch_bounds__(256, 6) void fused_layer(
    const unsigned* __restrict__ X,     // [N][64] uints (bf16 x rows)
    const int* __restrict__ col,
    const int* __restrict__ row_ptr,
    const unsigned* __restrict__ relb,
    const unsigned* __restrict__ Wt,    // [128][128] uints (bf16 [128][256])
    const float* __restrict__ cvec,
    float* outf,                        // fp32 out (layer 2) or nullptr
    unsigned* __restrict__ outb,        // bf16 X2 rows (layer 1) or nullptr
    int do_relu, int N) {
    __shared__ unsigned aggS[64 * 64];  // 16 KB: [64 nodes][128 bf16 agg]
    int tid = threadIdx.x;
    int w = tid >> 6;
    int lane = tid & 63;
    int nbase = blockIdx.x * 64;

    // ================= phase 1: gather =================
    {
        int g = lane >> 4;                   // edge slot 0..3
        int h = lane & 15;                   // dim chunk 0..15 (8 bf16 each)
        for (int i = 0; i < 16; ++i) {
            int n = nbase + w * 16 + i;
            if (n >= N) break;               // wave-uniform
            int beg = row_ptr[n];
            int end = row_ptr[n + 1];
            float s[8];
#pragma unroll
            for (int j = 0; j < 8; ++j) s[j] = 0.f;

            for (int base = beg; base < end; base += 64) {
                int ci = base + lane;
                unsigned cv = (unsigned)col[(ci < end) ? ci : beg];
                int mm = end - base; if (mm > 64) mm = 64;
                int e = 0;
                for (; e + 16 <= mm; e += 16) {
                    uint4 u[4], r[4];
#pragma unroll
                    for (int t = 0; t < 4; ++t) {
                        unsigned c = (unsigned)__shfl((int)cv, e + 4 * t + g, 64);
                        u[t] = ((const uint4*)(X + (size_t)(c & 0x1FFFFu) * 64))[h];
                        r[t] = ((const uint4*)(relb + (size_t)(c >> 17) * 64))[h];
                    }
#pragma unroll
                    for (int t = 0; t < 4; ++t) {
                        s[0] += blo(u[t].x) - blo(r[t].x);
                        s[1] += bhi(u[t].x) - bhi(r[t].x);
                        s[2] += blo(u[t].y) - blo(r[t].y);
                        s[3] += bhi(u[t].y) - bhi(r[t].y);
                        s[4] += blo(u[t].z) - blo(r[t].z);
                        s[5] += bhi(u[t].z) - bhi(r[t].z);
                        s[6] += blo(u[t].w) - blo(r[t].w);
                        s[7] += bhi(u[t].w) - bhi(r[t].w);
                    }
                }
                for (; e + 4 <= mm; e += 4) {
                    unsigned c = (unsigned)__shfl((int)cv, e + g, 64);
                    uint4 u = ((const uint4*)(X + (size_t)(c & 0x1FFFFu) * 64))[h];
                    uint4 r = ((const uint4*)(relb + (size_t)(c >> 17) * 64))[h];
                    s[0] += blo(u.x) - blo(r.x);
                    s[1] += bhi(u.x) - bhi(r.x);
                    s[2] += blo(u.y) - blo(r.y);
                    s[3] += bhi(u.y) - bhi(r.y);
                    s[4] += blo(u.z) - blo(r.z);
                    s[5] += bhi(u.z) - bhi(r.z);
                    s[6] += blo(u.w) - blo(r.w);
                    s[7] += bhi(u.w) - bhi(r.w);
                }
                if (e < mm) {
                    int idx = e + g;
                    unsigned c = (unsigned)__shfl((int)cv, (idx < mm) ? idx : 0, 64);
                    if (idx < mm) {
                        uint4 u = ((const uint4*)(X + (size_t)(c & 0x1FFFFu) * 64))[h];
                        uint4 r = ((const uint4*)(relb + (size_t)(c >> 17) * 64))[h];
                        s[0] += blo(u.x) - blo(r.x);
                        s[1] += bhi(u.x) - bhi(r.x);
                        s[2] += blo(u.y) - blo(r.y);
                        s[3] += bhi(u.y) - bhi(r.y);
                        s[4] += blo(u.z) - blo(r.z);
                        s[5] += bhi(u.z) - bhi(r.z);
                        s[6] += blo(u.w) - blo(r.w);
                        s[7] += bhi(u.w) - bhi(r.w);
                    }
                }
            }
#pragma unroll
            for (int j = 0; j < 8; ++j) {
                s[j] += __shfl_xor(s[j], 16, 64);
                s[j] += __shfl_xor(s[j], 32, 64);
            }
            if (g == 0) {
                uint4 o;
                o.x = bpack(s[0], s[1]);
                o.y = bpack(s[2], s[3]);
                o.z = bpack(s[4], s[5]);
                o.w = bpack(s[6], s[7]);
                int lr = w * 16 + i;
                // chunk kc = h>>3, 16B group q = h&7, swizzled by row
                *(uint4*)&aggS[lr * 64 + (h >> 3) * 32 + 4 * ((h & 7) ^ (lr & 7))] = o;
            }
        }
    }
    __syncthreads();   // safety only: each wave reads rows it wrote

    // ================= phase 2: GEMM (Wt direct from L2) =================
    int m = lane & 15;
    int quad = lane >> 4;
    f32x4 acc[8];
#pragma unroll
    for (int t = 0; t < 8; ++t) acc[t] = (f32x4)(0.f);

    int r0 = w * 16 + m;                 // local output row (node)
    int gr0 = nbase + r0;

    for (int kc = 0; kc < 4; ++kc) {
#pragma unroll
        for (int s = 0; s < 2; ++s) {
            int gq = s * 4 + quad;
            short8 b0;
            if (kc < 2) {
                b0 = *(const short8*)&aggS[r0 * 64 + kc * 32 + 4 * (gq ^ (r0 & 7))];
            } else {
                uint4 xv = make_uint4(0u, 0u, 0u, 0u);
                if (gr0 < N) xv = ((const uint4*)X)[(size_t)gr0 * 16 + (kc - 2) * 8 + gq];
                b0 = *(const short8*)&xv;
            }
#pragma unroll
            for (int t = 0; t < 8; ++t) {
                int jr = t * 16 + m;
                uint4 av = ((const uint4*)Wt)[jr * 32 + kc * 8 + gq];
                short8 a = *(const short8*)&av;
                acc[t] = __builtin_amdgcn_mfma_f32_16x16x32_bf16(a, b0, acc[t], 0, 0, 0);
            }
        }
    }

    // ================= epilogue =================
    if (gr0 < N) {
#pragma unroll
        for (int t = 0; t < 8; ++t) {
            float4 cv = ((const float4*)cvec)[t * 4 + quad];
            f32x4 a = acc[t];
            float v0 = a[0] + cv.x;
            float v1 = a[1] + cv.y;
            float v2 = a[2] + cv.z;
            float v3 = a[3] + cv.w;
            if (do_relu) {
                v0 = fmaxf(v0, 0.f); v1 = fmaxf(v1, 0.f);
                v2 = fmaxf(v2, 0.f); v3 = fmaxf(v3, 0.f);
            }
            if (outf) {
                ((float4*)outf)[(size_t)gr0 * 32 + t * 4 + quad] =
                    make_float4(v0, v1, v2, v3);
            } else {
                uint2 o;
                o.x = bpack(v0, v1);
                o.y = bpack(v2, v3);
                ((uint2*)(outb + (size_t)gr0 * 64))[t * 4 + quad] = o;
            }
        }
    }
}

extern "C" void kernel_launch(void* const* d_in, const int* in_sizes, int n_in,
                              void* d_out, int out_size, void* d_ws, size_t ws_size,
                              hipStream_t stream) {
    const float* x    = (const float*)d_in[0];
    const int*   ei   = (const int*)d_in[1];
    const int*   et   = (const int*)d_in[2];
    const float* WI1  = (const float*)d_in[3];
    const float* WO1  = (const float*)d_in[4];
    const float* rel1 = (const float*)d_in[5];
    const float* b1   = (const float*)d_in[6];
    const float* WI2  = (const float*)d_in[7];
    const float* WO2  = (const float*)d_in[8];
    const float* rel2 = (const float*)d_in[9];
    const float* b2   = (const float*)d_in[10];

    const int E = in_sizes[2];          // 800000
    const int N = in_sizes[0] / D;      // 50000
    const int* src = ei;
    const int* dst = ei + E;
    const int nCoarse = (N + 127) / 128;   // 391

    // workspace layout (uints)
    unsigned* wsu  = (unsigned*)d_ws;
    unsigned* X1   = wsu;                          // N*64 uints (12.8 MB)
    unsigned* X2   = X1 + (size_t)N * 64;          // N*64 uints (12.8 MB)
    unsigned* Wt1  = X2 + (size_t)N * 64;          // 16384
    unsigned* Wt2  = Wt1 + 16384;                  // 16384
    float*    cvec1 = (float*)(Wt2 + 16384);       // 128
    float*    cvec2 = cvec1 + D;                   // 128
    unsigned* rb1  = (unsigned*)(cvec2 + D);       // 237*64
    unsigned* rb2  = rb1 + 237 * 64;               // 237*64
    int*      coarseCnt  = (int*)(rb2 + 237 * 64); // nCoarse*16 padded (64B/counter)
    int*      row_ptr    = coarseCnt + 8192;       // N+4
    int*      col        = row_ptr + N + 4;        // E
    unsigned* bulk       = (unsigned*)(col + E);   // nCoarse*CAP (4.8 MB)

    const int relHalf = 237 * 32;                  // float4s per rel table
    const int B1B = (E + 4095) / 4096;             // 196
    const int CB = (N * 32 + 255) / 256;           // 6250
    const int RB = (2 * relHalf + 255) / 256;      // 60

    // ---- zero coarse counters (tiny), then one mega prep dispatch ----
    hipMemsetAsync(coarseCnt, 0, 8192 * sizeof(int), stream);
    setup_mega<<<B1B + CB + 128 + 1 + RB, 256, 0, stream>>>(
        x, src, dst, et, WI1, WO1, WI2, WO2, rel1, rel2, b1, b2,
        X1, Wt1, Wt2, cvec1, cvec2, rb1, rb2,
        coarseCnt, bulk, N, E, relHalf, nCoarse);

    // ---- CSR finish (scan fused into bucket2) ----
    bucket2<<<nCoarse, 256, 0, stream>>>(bulk, coarseCnt, row_ptr, col,
                                         N, E, nCoarse);

    const int fused_blocks = (N + 63) / 64;        // 782

    // ---- layer 1: gather X1 -> LDS; GEMM -> bf16 X2 ----
    fused_layer<<<fused_blocks, 256, 0, stream>>>(
        X1, col, row_ptr, rb1, Wt1, cvec1,
        (float*)nullptr, X2, 1, N);

    // ---- layer 2: gather X2 -> LDS; GEMM -> fp32 d_out ----
    fused_layer<<<fused_blocks, 256, 0, stream>>>(
        X2, col, row_ptr, rb2, Wt2, cvec2,
        (float*)d_out, (unsigned*)nullptr, 0, N);
}

// Round 7
// 218.392 us; speedup vs baseline: 5.4886x; 1.2572x over previous
//
#include <hip/hip_runtime.h>

#define D 128
#define CAP 3072        // coarse-bucket capacity (mean 2046, sigma ~45)

typedef __attribute__((ext_vector_type(8))) short short8;   // 8 bf16 (4 VGPRs)
typedef __attribute__((ext_vector_type(4))) float f32x4;    // MFMA acc

// bf16 helpers: packed storage = little-endian pairs in a uint (elem 2i = lo)
__device__ __forceinline__ float blo(unsigned w) { return __uint_as_float(w << 16); }
__device__ __forceinline__ float bhi(unsigned w) { return __uint_as_float(w & 0xFFFF0000u); }
__device__ __forceinline__ unsigned bpack(float a, float b) {   // RNE
    unsigned ua = __float_as_uint(a), ub = __float_as_uint(b);
    ua += 0x7FFFu + ((ua >> 16) & 1u);
    ub += 0x7FFFu + ((ub >> 16) & 1u);
    return (ua >> 16) | (ub & 0xFFFF0000u);
}

// ---------------------------------------------------------------------------
// setup_mega (r3-proven, byte-identical): ONE dispatch for prep + bucket1:
//   blocks [0, B1B)        : bucket1 (coarse sort, 4096 edges/block,
//                            64B-padded claim counters)
//   blocks [B1B, +CB)      : conv_x  (fp32 x -> bf16 x-part of A1)
//   blocks [.., +128)      : prep_w  (Wt bf16, 64 blocks per layer)
//   block  next            : prep_c  (cvec, both layers)
//   blocks [.., +RB)       : conv_rel (rel fp32 -> bf16)
// coarseCnt must be zeroed (hipMemsetAsync) before this kernel.
// ---------------------------------------------------------------------------
__global__ __launch_bounds__(256) void setup_mega(
    const float* __restrict__ x,
    const int* __restrict__ srcA, const int* __restrict__ dstA,
    const int* __restrict__ etA,
    const float* __restrict__ WI1, const float* __restrict__ WO1,
    const float* __restrict__ WI2, const float* __restrict__ WO2,
    const float* __restrict__ rel1, const float* __restrict__ rel2,
    const float* __restrict__ b1, const float* __restrict__ b2,
    unsigned* __restrict__ A1,
    unsigned* __restrict__ Wt1, unsigned* __restrict__ Wt2,
    float* __restrict__ c1, float* __restrict__ c2,
    unsigned* __restrict__ rb1, unsigned* __restrict__ rb2,
    int* __restrict__ coarseCnt, unsigned* __restrict__ bulk,
    int N, int E, int relHalf, int nCoarse) {
    int tid = threadIdx.x;
    int bx = blockIdx.x;
    const int B1B = (E + 4095) / 4096;

    if (bx < B1B) {                               // ---- bucket1 ----
        __shared__ unsigned pay[4096];
        __shared__ unsigned short ck[4096];
        __shared__ int hist[400];
        __shared__ int base[400];
        int e0 = bx * 4096;
        int cnt = E - e0; if (cnt > 4096) cnt = 4096;
        for (int i = tid; i < nCoarse; i += 256) hist[i] = 0;
        __syncthreads();
        for (int i = tid; i < cnt; i += 256) {
            int e = e0 + i;
            int d = dstA[e];
            pay[i] = (unsigned)srcA[e] | ((unsigned)etA[e] << 17) | ((unsigned)(d & 127) << 25);
            int c = d >> 7;
            ck[i] = (unsigned short)c;
            atomicAdd(&hist[c], 1);
        }
        __syncthreads();
        for (int i = tid; i < nCoarse; i += 256) {
            int h = hist[i];
            base[i] = (h > 0) ? (i * CAP + atomicAdd(&coarseCnt[i * 16], h)) : 0;
            hist[i] = 0;
        }
        __syncthreads();
        for (int i = tid; i < cnt; i += 256) {
            int c = ck[i];
            int pos = base[c] + atomicAdd(&hist[c], 1);
            bulk[pos] = pay[i];
        }
        return;
    }
    bx -= B1B;
    const int CB = (N * 32 + 255) / 256;
    if (bx < CB) {                                // ---- conv_x ----
        int idx = bx * 256 + tid;
        if (idx < N * 32) {
            int n = idx >> 5, q = idx & 31;
            float4 v = ((const float4*)x)[idx];
            uint2 o;
            o.x = bpack(v.x, v.y);
            o.y = bpack(v.z, v.w);
            *(uint2*)(A1 + (size_t)n * 128 + 64 + q * 2) = o;
        }
        return;
    }
    bx -= CB;
    if (bx < 128) {                               // ---- prep_w ----
        int layer = bx >> 6;
        const float* WI = layer ? WI2 : WI1;
        const float* WO = layer ? WO2 : WO1;
        unsigned* Wt = layer ? Wt2 : Wt1;
        int idx = (bx & 63) * 256 + tid;          // 0..16383
        int j = idx >> 7;
        int kk = idx & 127;
        int k0 = kk * 2;
        float a, b;
        if (k0 < D) {
            a = WI[j * D + k0];
            b = WI[j * D + k0 + 1];
        } else {
            int kx = k0 - D;
            a = WI[j * D + kx]     + WO[j * D + kx];
            b = WI[j * D + kx + 1] + WO[j * D + kx + 1];
        }
        Wt[idx] = bpack(a, b);
        return;
    }
    bx -= 128;
    if (bx == 0) {                                // ---- prep_c ----
        int layer = tid >> 7;
        int j = tid & (D - 1);
        const float* WI = layer ? WI2 : WI1;
        const float* b  = layer ? b2  : b1;
        const float* rl = layer ? rel2 : rel1;
        float s = b[j];
        for (int k = 0; k < D; ++k) s = fmaf(-WI[j * D + k], rl[k], s);
        (layer ? c2 : c1)[j] = s;
        return;
    }
    bx -= 1;
    {                                             // ---- conv_rel ----
        int idx = bx * 256 + tid;
        if (idx < 2 * relHalf) {
            const float* src = (idx < relHalf) ? rel1 : rel2;
            unsigned* dst = (idx < relHalf) ? rb1 : rb2;
            int k = (idx < relHalf) ? idx : idx - relHalf;
            float4 v = ((const float4*)src)[k];
            uint2 o;
            o.x = bpack(v.x, v.y);
            o.y = bpack(v.z, v.w);
            *(uint2*)(dst + (size_t)k * 2) = o;
        }
    }
}

// ---------------------------------------------------------------------------
// bucket2 (scan fused, r6-proven): one block per coarse bucket. Reduces the
// padded coarse counters below it for its global base (absorbs scan_coarse),
// fine-histograms 128 bins, scans, writes row_ptr, scatters to col.
// ---------------------------------------------------------------------------
__global__ __launch_bounds__(256) void bucket2(const unsigned* __restrict__ bulk,
                                               const int* __restrict__ coarseCnt,
                                               int* __restrict__ row_ptr,
                                               int* __restrict__ col,
                                               int N, int E, int nCoarse) {
    __shared__ unsigned pay[CAP];
    __shared__ int red[256];
    __shared__ int hist[128];
    __shared__ int cur[128];
    int c = blockIdx.x;
    int tid = threadIdx.x;
    int cnt = coarseCnt[c * 16];
    const unsigned* seg = bulk + (size_t)c * CAP;
    if (tid < 128) hist[tid] = 0;
    int sum = 0;
    for (int i = tid; i < c; i += 256) sum += coarseCnt[i * 16];
    red[tid] = sum;
    __syncthreads();
    for (int off = 128; off > 0; off >>= 1) {
        if (tid < off) red[tid] += red[tid + off];
        __syncthreads();
    }
    int cb = red[0];                        // exclusive coarse base
    for (int i = tid; i < cnt; i += 256) {
        unsigned v = seg[i];
        pay[i] = v;
        atomicAdd(&hist[v >> 25], 1);
    }
    __syncthreads();
    // exclusive scan of 128 fine bins (threads 0..127)
    int f = tid;
    int myCnt = (f < 128) ? hist[f] : 0;
    for (int off = 1; off < 128; off <<= 1) {
        int v = (f < 128 && f >= off) ? hist[f - off] : 0;
        __syncthreads();
        if (f < 128) hist[f] += v;
        __syncthreads();
    }
    if (f < 128) {
        int excl = hist[f] - myCnt;
        int d = (c << 7) + f;
        if (d < N) row_ptr[d] = cb + excl;
        cur[f] = cb + excl;
    }
    if (c == nCoarse - 1 && tid == 0) row_ptr[N] = E;
    __syncthreads();
    for (int i = tid; i < cnt; i += 256) {
        unsigned v = pay[i];
        int pos = atomicAdd(&cur[v >> 25], 1);
        col[pos] = (int)(v & 0x1FFFFFFu);
    }
}

// ---------------------------------------------------------------------------
// Gather v2 (r1/r3-proven, byte-identical): ONE WAVE (64 lanes) per node.
//   g = lane>>4 : edge slot (4 edges per load instruction)
//   h = lane&15 : 16B dim chunk (uint4 = 8 bf16) -> 16 lanes cover D=128
// col[] entries prefetched with ONE coalesced load, distributed via __shfl.
// ---------------------------------------------------------------------------
__global__ __launch_bounds__(256) void gather_kernel(const unsigned* __restrict__ Asrc,
                                                     const int* __restrict__ col,
                                                     const int* __restrict__ row_ptr,
                                                     const unsigned* __restrict__ relb,
                                                     unsigned* __restrict__ Adst, int N) {
    int n = blockIdx.x * 4 + (threadIdx.x >> 6);
    if (n >= N) return;                      // wave-uniform exit
    int lane = threadIdx.x & 63;
    int g = lane >> 4;                       // edge slot 0..3
    int h = lane & 15;                       // dim chunk 0..15
    int beg = row_ptr[n];
    int end = row_ptr[n + 1];
    float s[8];
#pragma unroll
    for (int j = 0; j < 8; ++j) s[j] = 0.f;

    for (int base = beg; base < end; base += 64) {
        int ci = base + lane;
        unsigned cv = (unsigned)col[(ci < end) ? ci : beg];   // always in-bounds
        int m = end - base; if (m > 64) m = 64;
        int e = 0;
        // ---- 16 edges per round: 8 x uint4 loads in flight per lane ----
        for (; e + 16 <= m; e += 16) {
            uint4 u[4], r[4];
#pragma unroll
            for (int t = 0; t < 4; ++t) {
                unsigned c = (unsigned)__shfl((int)cv, e + 4 * t + g, 64);
                u[t] = ((const uint4*)(Asrc + (size_t)(c & 0x1FFFFu) * 128 + 64))[h];
                r[t] = ((const uint4*)(relb + (size_t)(c >> 17) * 64))[h];
            }
#pragma unroll
            for (int t = 0; t < 4; ++t) {
                s[0] += blo(u[t].x) - blo(r[t].x);
                s[1] += bhi(u[t].x) - bhi(r[t].x);
                s[2] += blo(u[t].y) - blo(r[t].y);
                s[3] += bhi(u[t].y) - bhi(r[t].y);
                s[4] += blo(u[t].z) - blo(r[t].z);
                s[5] += bhi(u[t].z) - bhi(r[t].z);
                s[6] += blo(u[t].w) - blo(r[t].w);
                s[7] += bhi(u[t].w) - bhi(r[t].w);
            }
        }
        // ---- 4-edge steps ----
        for (; e + 4 <= m; e += 4) {
            unsigned c = (unsigned)__shfl((int)cv, e + g, 64);
            uint4 u = ((const uint4*)(Asrc + (size_t)(c & 0x1FFFFu) * 128 + 64))[h];
            uint4 r = ((const uint4*)(relb + (size_t)(c >> 17) * 64))[h];
            s[0] += blo(u.x) - blo(r.x);
            s[1] += bhi(u.x) - bhi(r.x);
            s[2] += blo(u.y) - blo(r.y);
            s[3] += bhi(u.y) - bhi(r.y);
            s[4] += blo(u.z) - blo(r.z);
            s[5] += bhi(u.z) - bhi(r.z);
            s[6] += blo(u.w) - blo(r.w);
            s[7] += bhi(u.w) - bhi(r.w);
        }
        // ---- partial group (shuffle BEFORE divergence) ----
        if (e < m) {
            int idx = e + g;
            unsigned c = (unsigned)__shfl((int)cv, (idx < m) ? idx : 0, 64);
            if (idx < m) {
                uint4 u = ((const uint4*)(Asrc + (size_t)(c & 0x1FFFFu) * 128 + 64))[h];
                uint4 r = ((const uint4*)(relb + (size_t)(c >> 17) * 64))[h];
                s[0] += blo(u.x) - blo(r.x);
                s[1] += bhi(u.x) - bhi(r.x);
                s[2] += blo(u.y) - blo(r.y);
                s[3] += bhi(u.y) - bhi(r.y);
                s[4] += blo(u.z) - blo(r.z);
                s[5] += bhi(u.z) - bhi(r.z);
                s[6] += blo(u.w) - blo(r.w);
                s[7] += bhi(u.w) - bhi(r.w);
            }
        }
    }
    // reduce across the 4 edge slots: lanes l, l^16, l^32 hold same dims
#pragma unroll
    for (int j = 0; j < 8; ++j) {
        s[j] += __shfl_xor(s[j], 16, 64);
        s[j] += __shfl_xor(s[j], 32, 64);
    }
    if (g == 0) {
        uint4 o;
        o.x = bpack(s[0], s[1]);
        o.y = bpack(s[2], s[3]);
        o.z = bpack(s[4], s[5]);
        o.w = bpack(s[6], s[7]);
        ((uint4*)(Adst + (size_t)n * 128))[h] = o;
    }
}

// ---------------------------------------------------------------------------
// MFMA node GEMM, 64-node tiles (r3 structure, M-tile halved for grid fill):
// out[n][j] = act( cvec[j] + sum_{k<256} A[n][k]*Wt[j][k] )
// Block: 256 thr = 4 waves x 16 nodes = 64 nodes; grid 782 (~3-6 blocks/CU
// vs 391/1.5 at 128-node tiles). LDS: WtS 16KB + AS 8KB = 24KB -> 6/CU cap.
// Same XOR-swizzled staging/fragment reads as the r3-proven 128-node kernel.
// ---------------------------------------------------------------------------
__global__ __launch_bounds__(256) void node_mfma(
    const unsigned* A,                  // [N][128] uints (bf16 [N][256])
    const unsigned* __restrict__ Wt,    // [128][128] uints (bf16 [128][256])
    const float* __restrict__ cvec,
    float* outf,                        // fp32 out (layer 2) or nullptr
    unsigned* __restrict__ outb,        // bf16 x-part of next A (layer 1) or nullptr
    int do_relu, int N) {
    __shared__ unsigned WtS[128 * 32];  // 16 KB
    __shared__ unsigned AS[64 * 32];    // 8 KB
    int tid = threadIdx.x;
    int w = tid >> 6;
    int lane = tid & 63;
    int m = lane & 15;
    int quad = lane >> 4;
    int nbase = blockIdx.x * 64;

    f32x4 acc[8];
#pragma unroll
    for (int t = 0; t < 8; ++t) acc[t] = (f32x4)(0.f);

    for (int kc = 0; kc < 4; ++kc) {
        for (int i = tid; i < 1024; i += 256) {
            int j = i >> 3, q = i & 7;
            uint4 v = ((const uint4*)Wt)[j * 32 + kc * 8 + q];
            *(uint4*)&WtS[j * 32 + 4 * (q ^ (j & 7))] = v;
        }
        for (int i = tid; i < 512; i += 256) {
            int n = i >> 3, q = i & 7;
            int gn = nbase + n;
            uint4 v = make_uint4(0u, 0u, 0u, 0u);
            if (gn < N) v = ((const uint4*)A)[(size_t)gn * 32 + kc * 8 + q];
            *(uint4*)&AS[n * 32 + 4 * (q ^ (n & 7))] = v;
        }
        __syncthreads();

#pragma unroll
        for (int s = 0; s < 2; ++s) {
            int g = s * 4 + quad;
            int r0 = w * 16 + m;
            short8 b0 = *(const short8*)&AS[r0 * 32 + 4 * (g ^ (r0 & 7))];
#pragma unroll
            for (int t = 0; t < 8; ++t) {
                int jr = t * 16 + m;
                short8 a = *(const short8*)&WtS[jr * 32 + 4 * (g ^ (jr & 7))];
                acc[t] = __builtin_amdgcn_mfma_f32_16x16x32_bf16(a, b0, acc[t], 0, 0, 0);
            }
        }
        __syncthreads();
    }

    int node = nbase + w * 16 + m;
    if (node < N) {
#pragma unroll
        for (int t = 0; t < 8; ++t) {
            float4 cv = ((const float4*)cvec)[t * 4 + quad];
            f32x4 a = acc[t];
            float v0 = a[0] + cv.x;
            float v1 = a[1] + cv.y;
            float v2 = a[2] + cv.z;
            float v3 = a[3] + cv.w;
            if (do_relu) {
                v0 = fmaxf(v0, 0.f); v1 = fmaxf(v1, 0.f);
                v2 = fmaxf(v2, 0.f); v3 = fmaxf(v3, 0.f);
            }
            if (outf) {
                ((float4*)outf)[(size_t)node * 32 + t * 4 + quad] =
                    make_float4(v0, v1, v2, v3);
            } else {
                uint2 o;
                o.x = bpack(v0, v1);
                o.y = bpack(v2, v3);
                ((uint2*)(outb + (size_t)node * 128))[32 + t * 4 + quad] = o;
            }
        }
    }
}

extern "C" void kernel_launch(void* const* d_in, const int* in_sizes, int n_in,
                              void* d_out, int out_size, void* d_ws, size_t ws_size,
                              hipStream_t stream) {
    const float* x    = (const float*)d_in[0];
    const int*   ei   = (const int*)d_in[1];
    const int*   et   = (const int*)d_in[2];
    const float* WI1  = (const float*)d_in[3];
    const float* WO1  = (const float*)d_in[4];
    const float* rel1 = (const float*)d_in[5];
    const float* b1   = (const float*)d_in[6];
    const float* WI2  = (const float*)d_in[7];
    const float* WO2  = (const float*)d_in[8];
    const float* rel2 = (const float*)d_in[9];
    const float* b2   = (const float*)d_in[10];

    const int E = in_sizes[2];          // 800000
    const int N = in_sizes[0] / D;      // 50000
    const int* src = ei;
    const int* dst = ei + E;
    const int nCoarse = (N + 127) / 128;   // 391

    // workspace layout (uints), A2 lives in d_out
    unsigned* wsu  = (unsigned*)d_ws;
    unsigned* A1   = wsu;                          // N*128 uints (25.6 MB)
    unsigned* Wt1  = A1 + (size_t)N * 128;         // 16384
    unsigned* Wt2  = Wt1 + 16384;                  // 16384
    float*    cvec1 = (float*)(Wt2 + 16384);       // 128
    float*    cvec2 = cvec1 + D;                   // 128
    unsigned* rb1  = (unsigned*)(cvec2 + D);       // 237*64
    unsigned* rb2  = rb1 + 237 * 64;               // 237*64
    int*      coarseCnt  = (int*)(rb2 + 237 * 64); // nCoarse*16 padded (64B/counter)
    int*      row_ptr    = coarseCnt + 8192;       // N+4
    int*      col        = row_ptr + N + 4;        // E
    unsigned* bulk       = (unsigned*)(col + E);   // nCoarse*CAP (4.8 MB)

    unsigned* A2 = (unsigned*)d_out;               // [N][128] uints -> fp32 out

    const int relHalf = 237 * 32;                  // float4s per rel table
    const int B1B = (E + 4095) / 4096;             // 196
    const int CB = (N * 32 + 255) / 256;           // 6250
    const int RB = (2 * relHalf + 255) / 256;      // 60

    // ---- zero coarse counters (tiny), then one mega prep dispatch ----
    hipMemsetAsync(coarseCnt, 0, 8192 * sizeof(int), stream);
    setup_mega<<<B1B + CB + 128 + 1 + RB, 256, 0, stream>>>(
        x, src, dst, et, WI1, WO1, WI2, WO2, rel1, rel2, b1, b2,
        A1, Wt1, Wt2, cvec1, cvec2, rb1, rb2,
        coarseCnt, bulk, N, E, relHalf, nCoarse);

    // ---- CSR finish (scan fused into bucket2) ----
    bucket2<<<nCoarse, 256, 0, stream>>>(bulk, coarseCnt, row_ptr, col,
                                         N, E, nCoarse);

    const int gather_blocks = (N + 3) / 4;         // 12500
    const int node_blocks = (N + 63) / 64;         // 782

    // ---- layer 1: gather x-part of A1 -> agg part of A1; node -> x-part of A2
    gather_kernel<<<gather_blocks, 256, 0, stream>>>(A1, col, row_ptr, rb1, A1, N);
    node_mfma<<<node_blocks, 256, 0, stream>>>(A1, Wt1, cvec1,
                                               (float*)nullptr, A2, 1, N);

    // ---- layer 2: gather x-part of A2 -> agg part of A2; node -> fp32 d_out
    gather_kernel<<<gather_blocks, 256, 0, stream>>>(A2, col, row_ptr, rb2, A2, N);
    node_mfma<<<node_blocks, 256, 0, stream>>>(A2, Wt2, cvec2,
                                               (float*)d_out, (unsigned*)nullptr, 0, N);
}